// Round 25
// baseline (185.118 us; speedup 1.0000x reference)
//
#include <hip/hip_runtime.h>

// ---------------------------------------------------------------------------
// TextGraphSAGE: 2-layer SAGEConv (mean aggr), N=50000, D=768, H=128, C=4,
// E=800000.
//  - project BEFORE aggregating (mean commutes with linear map)
//  - CSR gather instead of scatter atomics (r1: 102M float atomics = 77%)
//  - r17: atomic-free slot fill; r18: r8 gemm engine; r22/r23: count+fill
//    hidden under gemm slices; r24: sage1 2-deep pipeline.
//  - r25: UNEVEN gemm split -- A = 600 tiles + count (count needs only
//    ~13us of cover), B = 182 tiles + fill (1:5 pattern, 1024-edge chunks).
//    Removes ~30us of wasted even-split overhang.
// ---------------------------------------------------------------------------

typedef __bf16 bf16x8 __attribute__((ext_vector_type(8)));
typedef float  f32x4  __attribute__((ext_vector_type(4)));

__device__ __forceinline__ float bf16_lo(uint32_t w) {
    union { uint32_t u; float f; } c; c.u = w << 16; return c.f;
}
__device__ __forceinline__ float bf16_hi(uint32_t w) {
    union { uint32_t u; float f; } c; c.u = w & 0xffff0000u; return c.f;
}

// ---- prep: pack W into fragment-major bf16 Bp[kg][col][8] (kg=k/8, 96x256x8)
//      element (col,k) -> Bp[(k>>3)*2048 + col*8 + (k&7)]; also zero deg.
__global__ __launch_bounds__(256)
void prep(const float* __restrict__ W1l, const float* __restrict__ W1r,
          __bf16* __restrict__ Bp, int* __restrict__ deg, int N)
{
    int i = blockIdx.x * 256 + threadIdx.x;
    if (i < N) deg[i] = 0;
    if (i < 256 * 768) {
        int col = i / 768, k = i - col * 768;
        float v = (col < 128) ? W1l[col * 768 + k] : W1r[(col - 128) * 768 + k];
        Bp[((k >> 3) << 11) + (col << 3) + (k & 7)] = (__bf16)v;
    }
}

// ---- scan step 1: per-1024-block exclusive scan + block totals
__global__ __launch_bounds__(1024)
void scan1(const int* __restrict__ deg, int* __restrict__ row_ptr,
           int* __restrict__ partials, int N)
{
    __shared__ int buf[1024];
    int i = blockIdx.x * 1024 + threadIdx.x;
    int v = (i < N) ? deg[i] : 0;
    int val = v;
    buf[threadIdx.x] = val;
    __syncthreads();
    for (int off = 1; off < 1024; off <<= 1) {
        int t = (threadIdx.x >= (unsigned)off) ? buf[threadIdx.x - off] : 0;
        __syncthreads();
        val += t;
        buf[threadIdx.x] = val;
        __syncthreads();
    }
    if (i < N) row_ptr[i] = val - v;
    if (threadIdx.x == 1023) partials[blockIdx.x] = val;
}

// ---- scan steps 2+3 merged
__global__ __launch_bounds__(1024)
void scan23(int* __restrict__ row_ptr, const int* __restrict__ partials,
            int N, int E, int nb)
{
    __shared__ int soff;
    int b = blockIdx.x;
    if (threadIdx.x < 64) {
        int lane = threadIdx.x;
        int v = (lane < nb) ? partials[lane] : 0;
        int s = v;
        #pragma unroll
        for (int off = 1; off < 64; off <<= 1) {
            int t = __shfl_up(s, off);
            if (lane >= off) s += t;
        }
        if (lane == b) soff = s - v;
    }
    __syncthreads();
    int off = soff;
    int i = b * 1024 + threadIdx.x;
    if (i < N) row_ptr[i] += off;
    if (b == 0 && threadIdx.x == 0) row_ptr[N] = E;
}

// ---- the r8 gemm engine body (shared by both mixed kernels)
__device__ __forceinline__
void gemm_tile(const float* __restrict__ A, const __bf16* __restrict__ Bp,
               __bf16* __restrict__ Cb, int M, int bm, int tid,
               __bf16 (*As)[72])
{
    const int lane = tid & 63;
    const int wave = tid >> 6;               // 0..7
    const int wr = wave >> 2, wc = wave & 3; // wave tile: 32 rows x 64 cols
    const int l15 = lane & 15;
    const int lk  = lane >> 4;               // 0..3

    f32x4 acc[2][4] = {};
    float4 apref[2];

    const int arow = tid >> 3;               // 0..63
    const int akc  = (tid & 7) << 3;         // 0..56
    const __bf16* bbase = Bp + ((size_t)(wc * 64 + l15) << 3) + ((size_t)lk << 11);

    auto load_A = [&](int k0) {
        if (bm + arow < M) {
            const float* src = A + (size_t)(bm + arow) * 768 + k0 + akc;
            apref[0] = *(const float4*)src;
            apref[1] = *(const float4*)(src + 4);
        } else {
            apref[0] = make_float4(0.f, 0.f, 0.f, 0.f);
            apref[1] = make_float4(0.f, 0.f, 0.f, 0.f);
        }
    };

    load_A(0);
    for (int kt = 0; kt < 12; ++kt) {
        if (kt) __syncthreads();             // MFMA of kt-1 done with LDS
        {
            float4 f0 = apref[0], f1 = apref[1];
            bf16x8 bb;
            bb[0] = (__bf16)f0.x; bb[1] = (__bf16)f0.y;
            bb[2] = (__bf16)f0.z; bb[3] = (__bf16)f0.w;
            bb[4] = (__bf16)f1.x; bb[5] = (__bf16)f1.y;
            bb[6] = (__bf16)f1.z; bb[7] = (__bf16)f1.w;
            *(bf16x8*)&As[arow][akc] = bb;
        }
        __syncthreads();
        if (kt < 11) load_A((kt + 1) * 64);  // A burst in flight across MFMA

        bf16x8 bcur[2][4];
        #pragma unroll
        for (int ks = 0; ks < 2; ++ks)
            #pragma unroll
            for (int j = 0; j < 4; ++j)
                bcur[ks][j] = *(const bf16x8*)(bbase +
                    (((size_t)(kt * 8 + ks * 4) << 11) + ((size_t)j << 7)));

        #pragma unroll
        for (int ks = 0; ks < 2; ++ks) {
            int koff = ks * 32 + lk * 8;
            bf16x8 af[2];
            #pragma unroll
            for (int i = 0; i < 2; ++i)
                af[i] = *(const bf16x8*)&As[wr * 32 + i * 16 + l15][koff];
            #pragma unroll
            for (int i = 0; i < 2; ++i)
                #pragma unroll
                for (int j = 0; j < 4; ++j)
                    acc[i][j] = __builtin_amdgcn_mfma_f32_16x16x32_bf16(
                        af[i], bcur[ks][j], acc[i][j], 0, 0, 0);
        }
    }

    // coalesced C epilogue: 4 passes of 64 cols reusing As.
    // C/D layout: col = lane&15, row = (lane>>4)*4 + reg  [m89-verified]
    #pragma unroll
    for (int qtr = 0; qtr < 4; ++qtr) {
        __syncthreads();
        if (wc == qtr) {
            #pragma unroll
            for (int i = 0; i < 2; ++i)
                #pragma unroll
                for (int j = 0; j < 4; ++j)
                    #pragma unroll
                    for (int v = 0; v < 4; ++v)
                        As[wr * 32 + i * 16 + lk * 4 + v][j * 16 + l15] =
                            (__bf16)acc[i][j][v];
        }
        __syncthreads();
        int row = tid >> 3, ch = tid & 7;
        if (bm + row < M)
            *(bf16x8*)(Cb + (size_t)(bm + row) * 256 + qtr * 64 + ch * 8) =
                *(const bf16x8*)&As[row][ch * 8];
    }
}

// ---- dispatch A: b%5==0 -> gemm tile (b/5), else csr_count chunk (512 e)
__global__ __launch_bounds__(512)
void gemm_count(const float* __restrict__ A, const __bf16* __restrict__ Bp,
                __bf16* __restrict__ Cb, int M,
                const int* __restrict__ ei, int* __restrict__ deg,
                int* __restrict__ slot, int E)
{
    __shared__ __bf16 As[64][72];            // 9.2 KB
    const int tid = threadIdx.x;
    const int b  = blockIdx.x;
    const int g5 = b / 5, m5 = b - g5 * 5;

    if (m5 != 0) {
        int e = (g5 * 4 + (m5 - 1)) * 512 + tid;
        if (e < E) slot[e] = atomicAdd(&deg[ei[E + e]], 1);
        return;
    }
    gemm_tile(A, Bp, Cb, M, g5 * 64, tid, As);
}

// ---- dispatch B: b%6==0 -> gemm tile (gstart + b/6), else fill chunk
// (1024 edges: thread handles e=base+tid and base+512+tid), atomic-free.
__global__ __launch_bounds__(512)
void gemm_fillk(const float* __restrict__ A, const __bf16* __restrict__ Bp,
                __bf16* __restrict__ Cb, int M, int gstart,
                const int* __restrict__ ei, const int* __restrict__ row_ptr,
                const int* __restrict__ slot, int* __restrict__ csr_src, int E)
{
    __shared__ __bf16 As[64][72];            // 9.2 KB
    const int tid = threadIdx.x;
    const int b  = blockIdx.x;
    const int g6 = b / 6, m6 = b - g6 * 6;

    if (m6 != 0) {
        int base = (g6 * 5 + (m6 - 1)) * 1024;
        #pragma unroll
        for (int it = 0; it < 2; ++it) {
            int e = base + it * 512 + tid;
            if (e < E)
                csr_src[row_ptr[ei[E + e]] + slot[e]] = ei[e];
        }
        return;
    }
    gemm_tile(A, Bp, Cb, M, (gstart + g6) * 64, tid, As);
}

// ---- layer 1 + layer-2 projection, fused. One wave per node.
// 8 lanes per edge x 32B/lane; inner loop pipelined x2 (r24-proven).
__global__ __launch_bounds__(256)
void sage1_fused(const int* __restrict__ row_ptr, const int* __restrict__ csr_src,
                 const __bf16* __restrict__ pq, const float* __restrict__ b1,
                 const float* __restrict__ W2l, const float* __restrict__ W2r,
                 float* __restrict__ r, float* __restrict__ s, int N)
{
    __shared__ float Wl[512], Wr[512];
    for (int i = threadIdx.x; i < 512; i += 256) {
        Wl[i] = W2l[i];
        Wr[i] = W2r[i];
    }
    __syncthreads();

    int wid  = threadIdx.x >> 6;
    int lane = threadIdx.x & 63;
    int g = lane >> 3;          // edge slot 0..7
    int l = lane & 7;           // feature block 0..7
    int n = blockIdx.x * 4 + wid;
    if (n >= N) return;
    int beg = row_ptr[n], end = row_ptr[n + 1];

    float a0[8] = {}, a1[8] = {};   // feats l*8+j and 64+l*8+j
    for (int eb = beg; eb < end; eb += 64) {
        int cnt = min(64, end - eb);
        int id = (eb + lane < end) ? csr_src[eb + lane] : 0;
        for (int t = 0; t < cnt; t += 16) {
            int src0 = __shfl(id, t + g);
            int src1 = __shfl(id, t + 8 + g);
            bool ok0 = (t + g < cnt);
            bool ok1 = (t + 8 + g < cnt);
            const __bf16* row0 = pq + (size_t)src0 * 256;
            const __bf16* row1 = pq + (size_t)src1 * 256;
            uint4 w0a, w1a, w0b, w1b;
            if (ok0) {
                w0a = *(const uint4*)(row0 + l * 8);
                w1a = *(const uint4*)(row0 + 64 + l * 8);
            }
            if (ok1) {
                w0b = *(const uint4*)(row1 + l * 8);
                w1b = *(const uint4*)(row1 + 64 + l * 8);
            }
            if (ok0) {
                a0[0] += bf16_lo(w0a.x); a0[1] += bf16_hi(w0a.x);
                a0[2] += bf16_lo(w0a.y); a0[3] += bf16_hi(w0a.y);
                a0[4] += bf16_lo(w0a.z); a0[5] += bf16_hi(w0a.z);
                a0[6] += bf16_lo(w0a.w); a0[7] += bf16_hi(w0a.w);
                a1[0] += bf16_lo(w1a.x); a1[1] += bf16_hi(w1a.x);
                a1[2] += bf16_lo(w1a.y); a1[3] += bf16_hi(w1a.y);
                a1[4] += bf16_lo(w1a.z); a1[5] += bf16_hi(w1a.z);
                a1[6] += bf16_lo(w1a.w); a1[7] += bf16_hi(w1a.w);
            }
            if (ok1) {
                a0[0] += bf16_lo(w0b.x); a0[1] += bf16_hi(w0b.x);
                a0[2] += bf16_lo(w0b.y); a0[3] += bf16_hi(w0b.y);
                a0[4] += bf16_lo(w0b.z); a0[5] += bf16_hi(w0b.z);
                a0[6] += bf16_lo(w0b.w); a0[7] += bf16_hi(w0b.w);
                a1[0] += bf16_lo(w1b.x); a1[1] += bf16_hi(w1b.x);
                a1[2] += bf16_lo(w1b.y); a1[3] += bf16_hi(w1b.y);
                a1[4] += bf16_lo(w1b.z); a1[5] += bf16_hi(w1b.z);
                a1[6] += bf16_lo(w1b.w); a1[7] += bf16_hi(w1b.w);
            }
        }
    }
    #pragma unroll
    for (int c = 0; c < 8; ++c) {
        a0[c] += __shfl_xor(a0[c], 8);  a1[c] += __shfl_xor(a1[c], 8);
        a0[c] += __shfl_xor(a0[c], 16); a1[c] += __shfl_xor(a1[c], 16);
        a0[c] += __shfl_xor(a0[c], 32); a1[c] += __shfl_xor(a1[c], 32);
    }

    float inv = 1.0f / fmaxf((float)(end - beg), 1.0f);
    const __bf16* qrow = pq + (size_t)n * 256 + 128;
    uint4  qw0 = *(const uint4*)(qrow + l * 8);
    uint4  qw1 = *(const uint4*)(qrow + 64 + l * 8);
    float4 bv00 = *(const float4*)(b1 + l * 8);
    float4 bv01 = *(const float4*)(b1 + l * 8 + 4);
    float4 bv10 = *(const float4*)(b1 + 64 + l * 8);
    float4 bv11 = *(const float4*)(b1 + 64 + l * 8 + 4);
    float h0[8], h1[8];
    h0[0] = fmaxf(a0[0] * inv + bv00.x + bf16_lo(qw0.x), 0.f);
    h0[1] = fmaxf(a0[1] * inv + bv00.y + bf16_hi(qw0.x), 0.f);
    h0[2] = fmaxf(a0[2] * inv + bv00.z + bf16_lo(qw0.y), 0.f);
    h0[3] = fmaxf(a0[3] * inv + bv00.w + bf16_hi(qw0.y), 0.f);
    h0[4] = fmaxf(a0[4] * inv + bv01.x + bf16_lo(qw0.z), 0.f);
    h0[5] = fmaxf(a0[5] * inv + bv01.y + bf16_hi(qw0.z), 0.f);
    h0[6] = fmaxf(a0[6] * inv + bv01.z + bf16_lo(qw0.w), 0.f);
    h0[7] = fmaxf(a0[7] * inv + bv01.w + bf16_hi(qw0.w), 0.f);
    h1[0] = fmaxf(a1[0] * inv + bv10.x + bf16_lo(qw1.x), 0.f);
    h1[1] = fmaxf(a1[1] * inv + bv10.y + bf16_hi(qw1.x), 0.f);
    h1[2] = fmaxf(a1[2] * inv + bv10.z + bf16_lo(qw1.y), 0.f);
    h1[3] = fmaxf(a1[3] * inv + bv10.w + bf16_hi(qw1.y), 0.f);
    h1[4] = fmaxf(a1[4] * inv + bv11.x + bf16_lo(qw1.z), 0.f);
    h1[5] = fmaxf(a1[5] * inv + bv11.y + bf16_hi(qw1.z), 0.f);
    h1[6] = fmaxf(a1[6] * inv + bv11.z + bf16_lo(qw1.w), 0.f);
    h1[7] = fmaxf(a1[7] * inv + bv11.w + bf16_hi(qw1.w), 0.f);

    float part[8];
    #pragma unroll
    for (int c = 0; c < 4; ++c) {
        float pl = 0.f, pr = 0.f;
        #pragma unroll
        for (int j = 0; j < 8; ++j) {
            pl = fmaf(h0[j], Wl[c * 128 + l * 8 + j], pl);
            pl = fmaf(h1[j], Wl[c * 128 + 64 + l * 8 + j], pl);
            pr = fmaf(h0[j], Wr[c * 128 + l * 8 + j], pr);
            pr = fmaf(h1[j], Wr[c * 128 + 64 + l * 8 + j], pr);
        }
        part[c] = pl; part[4 + c] = pr;
    }
    #pragma unroll
    for (int off = 4; off; off >>= 1)
        #pragma unroll
        for (int c = 0; c < 8; ++c)
            part[c] += __shfl_xor(part[c], off);
    if (lane == 0) {
        *(float4*)(r + (size_t)n * 4) = make_float4(part[0], part[1], part[2], part[3]);
        *(float4*)(s + (size_t)n * 4) = make_float4(part[4], part[5], part[6], part[7]);
    }
}

// ---- layer 2: out[n] = mean_{src} r[src] + b2 + s[n]
__global__ __launch_bounds__(256)
void sage2_gather(const int* __restrict__ row_ptr, const int* __restrict__ csr_src,
                  const float* __restrict__ r, const float* __restrict__ s,
                  const float* __restrict__ b2, float* __restrict__ out, int N)
{
    int t = blockIdx.x * 256 + threadIdx.x;
    if (t >= N * 4) return;
    int n = t >> 2, c = t & 3;
    int beg = row_ptr[n], end = row_ptr[n + 1];
    float acc = 0.f;
    for (int e = beg; e < end; ++e)
        acc += r[(size_t)csr_src[e] * 4 + c];
    out[t] = acc / fmaxf((float)(end - beg), 1.0f) + b2[c] + s[t];
}

extern "C" void kernel_launch(void* const* d_in, const int* in_sizes, int n_in,
                              void* d_out, int out_size, void* d_ws, size_t ws_size,
                              hipStream_t stream)
{
    const float* x   = (const float*)d_in[0];
    const int*   ei  = (const int*)d_in[1];
    const float* W1l = (const float*)d_in[2];
    const float* b1l = (const float*)d_in[3];
    const float* W1r = (const float*)d_in[4];
    const float* W2l = (const float*)d_in[5];
    const float* b2l = (const float*)d_in[6];
    const float* W2r = (const float*)d_in[7];
    float* out = (float*)d_out;

    const int N = in_sizes[0] / 768;   // 50000
    const int E = in_sizes[1] / 2;     // 800000
    const int NB = (N + 1023) / 1024;  // 49 scan blocks
    const int gblocks = (N + 63) / 64; // 782 gemm tiles (BN=256 full width)
    const int gA = 600;                // dispatch A tiles (count cover)
    const int gB = gblocks - gA;       // 182 dispatch B tiles (fill cover)
    // A: 4 chunks/tile x 512e = 1.23M cap >= 800K. B: 5 chunks/tile x 1024e
    // = 932K cap >= 800K. Both guarded by e<E.

    char* ws = (char*)d_ws;
    size_t off = 0;
    auto alloc = [&](size_t bytes) -> void* {
        void* pp = ws + off;
        off += (bytes + 255) & ~(size_t)255;
        return pp;
    };
    __bf16* pq      = (__bf16*)alloc((size_t)N * 256 * 2);
    float*  r       = (float*)alloc((size_t)N * 4 * 4);
    float*  s       = (float*)alloc((size_t)N * 4 * 4);
    __bf16* Bp      = (__bf16*)alloc((size_t)256 * 768 * 2);
    int*    deg     = (int*)alloc((size_t)N * 4);
    int*    row_ptr = (int*)alloc((size_t)(N + 1) * 4);
    int*    slot    = (int*)alloc((size_t)E * 4);
    int*    csr_src = (int*)alloc((size_t)E * 4);
    int*    partials= (int*)alloc((size_t)64 * 4);

    // ---- pack W fragment-major bf16 + zero deg
    prep<<<(256 * 768 + 255) / 256, 256, 0, stream>>>(W1l, W1r, Bp, deg, N);

    // ---- dispatch A: gemm tiles 0..599 + ALL csr_count chunks
    gemm_count<<<gA * 5, 512, 0, stream>>>(x, Bp, pq, N, ei, deg, slot, E);

    // ---- scans (only serial CSR cost left)
    scan1<<<NB, 1024, 0, stream>>>(deg, row_ptr, partials, N);
    scan23<<<NB, 1024, 0, stream>>>(row_ptr, partials, N, E, NB);

    // ---- dispatch B: gemm tiles 600..781 + ALL csr_fill chunks
    gemm_fillk<<<gB * 6, 512, 0, stream>>>(x, Bp, pq, N, gA,
                                           ei, row_ptr, slot, csr_src, E);

    // ---- layer 1 aggregate + epilogue + layer-2 projection (fused)
    sage1_fused<<<(N + 3) / 4, 256, 0, stream>>>(row_ptr, csr_src, pq, b1l,
                                                 W2l, W2r, r, s, N);

    // ---- layer 2 aggregate + epilogue
    sage2_gather<<<(N * 4 + 255) / 256, 256, 0, stream>>>(row_ptr, csr_src, r, s, b2l, out, N);
}

// Round 26
// 184.572 us; speedup vs baseline: 1.0030x; 1.0030x over previous
//
#include <hip/hip_runtime.h>

// ---------------------------------------------------------------------------
// TextGraphSAGE: 2-layer SAGEConv (mean aggr), N=50000, D=768, H=128, C=4,
// E=800000.
//  - project BEFORE aggregating (mean commutes with linear map)
//  - CSR gather instead of scatter atomics (r1: 102M float atomics = 77%)
//  - r17: atomic-free slot fill; r18: r8 gemm engine; r22/r23: count+fill
//    hidden under gemm slices; r24: sage1 2-deep pipeline.
//  - r25: UNEVEN gemm split -- A = 600 tiles + count (count needs only
//    ~13us of cover), B = 182 tiles + fill (1:5 pattern, 1024-edge chunks).
//    Removes ~30us of wasted even-split overhang.
// ---------------------------------------------------------------------------

typedef __bf16 bf16x8 __attribute__((ext_vector_type(8)));
typedef float  f32x4  __attribute__((ext_vector_type(4)));

__device__ __forceinline__ float bf16_lo(uint32_t w) {
    union { uint32_t u; float f; } c; c.u = w << 16; return c.f;
}
__device__ __forceinline__ float bf16_hi(uint32_t w) {
    union { uint32_t u; float f; } c; c.u = w & 0xffff0000u; return c.f;
}

// ---- prep: pack W into fragment-major bf16 Bp[kg][col][8] (kg=k/8, 96x256x8)
//      element (col,k) -> Bp[(k>>3)*2048 + col*8 + (k&7)]; also zero deg.
__global__ __launch_bounds__(256)
void prep(const float* __restrict__ W1l, const float* __restrict__ W1r,
          __bf16* __restrict__ Bp, int* __restrict__ deg, int N)
{
    int i = blockIdx.x * 256 + threadIdx.x;
    if (i < N) deg[i] = 0;
    if (i < 256 * 768) {
        int col = i / 768, k = i - col * 768;
        float v = (col < 128) ? W1l[col * 768 + k] : W1r[(col - 128) * 768 + k];
        Bp[((k >> 3) << 11) + (col << 3) + (k & 7)] = (__bf16)v;
    }
}

// ---- scan step 1: per-1024-block exclusive scan + block totals
__global__ __launch_bounds__(1024)
void scan1(const int* __restrict__ deg, int* __restrict__ row_ptr,
           int* __restrict__ partials, int N)
{
    __shared__ int buf[1024];
    int i = blockIdx.x * 1024 + threadIdx.x;
    int v = (i < N) ? deg[i] : 0;
    int val = v;
    buf[threadIdx.x] = val;
    __syncthreads();
    for (int off = 1; off < 1024; off <<= 1) {
        int t = (threadIdx.x >= (unsigned)off) ? buf[threadIdx.x - off] : 0;
        __syncthreads();
        val += t;
        buf[threadIdx.x] = val;
        __syncthreads();
    }
    if (i < N) row_ptr[i] = val - v;
    if (threadIdx.x == 1023) partials[blockIdx.x] = val;
}

// ---- scan steps 2+3 merged
__global__ __launch_bounds__(1024)
void scan23(int* __restrict__ row_ptr, const int* __restrict__ partials,
            int N, int E, int nb)
{
    __shared__ int soff;
    int b = blockIdx.x;
    if (threadIdx.x < 64) {
        int lane = threadIdx.x;
        int v = (lane < nb) ? partials[lane] : 0;
        int s = v;
        #pragma unroll
        for (int off = 1; off < 64; off <<= 1) {
            int t = __shfl_up(s, off);
            if (lane >= off) s += t;
        }
        if (lane == b) soff = s - v;
    }
    __syncthreads();
    int off = soff;
    int i = b * 1024 + threadIdx.x;
    if (i < N) row_ptr[i] += off;
    if (b == 0 && threadIdx.x == 0) row_ptr[N] = E;
}

// ---- the r8 gemm engine body (shared by both mixed kernels)
__device__ __forceinline__
void gemm_tile(const float* __restrict__ A, const __bf16* __restrict__ Bp,
               __bf16* __restrict__ Cb, int M, int bm, int tid,
               __bf16 (*As)[72])
{
    const int lane = tid & 63;
    const int wave = tid >> 6;               // 0..7
    const int wr = wave >> 2, wc = wave & 3; // wave tile: 32 rows x 64 cols
    const int l15 = lane & 15;
    const int lk  = lane >> 4;               // 0..3

    f32x4 acc[2][4] = {};
    float4 apref[2];

    const int arow = tid >> 3;               // 0..63
    const int akc  = (tid & 7) << 3;         // 0..56
    const __bf16* bbase = Bp + ((size_t)(wc * 64 + l15) << 3) + ((size_t)lk << 11);

    auto load_A = [&](int k0) {
        if (bm + arow < M) {
            const float* src = A + (size_t)(bm + arow) * 768 + k0 + akc;
            apref[0] = *(const float4*)src;
            apref[1] = *(const float4*)(src + 4);
        } else {
            apref[0] = make_float4(0.f, 0.f, 0.f, 0.f);
            apref[1] = make_float4(0.f, 0.f, 0.f, 0.f);
        }
    };

    load_A(0);
    for (int kt = 0; kt < 12; ++kt) {
        if (kt) __syncthreads();             // MFMA of kt-1 done with LDS
        {
            float4 f0 = apref[0], f1 = apref[1];
            bf16x8 bb;
            bb[0] = (__bf16)f0.x; bb[1] = (__bf16)f0.y;
            bb[2] = (__bf16)f0.z; bb[3] = (__bf16)f0.w;
            bb[4] = (__bf16)f1.x; bb[5] = (__bf16)f1.y;
            bb[6] = (__bf16)f1.z; bb[7] = (__bf16)f1.w;
            *(bf16x8*)&As[arow][akc] = bb;
        }
        __syncthreads();
        if (kt < 11) load_A((kt + 1) * 64);  // A burst in flight across MFMA

        bf16x8 bcur[2][4];
        #pragma unroll
        for (int ks = 0; ks < 2; ++ks)
            #pragma unroll
            for (int j = 0; j < 4; ++j)
                bcur[ks][j] = *(const bf16x8*)(bbase +
                    (((size_t)(kt * 8 + ks * 4) << 11) + ((size_t)j << 7)));

        #pragma unroll
        for (int ks = 0; ks < 2; ++ks) {
            int koff = ks * 32 + lk * 8;
            bf16x8 af[2];
            #pragma unroll
            for (int i = 0; i < 2; ++i)
                af[i] = *(const bf16x8*)&As[wr * 32 + i * 16 + l15][koff];
            #pragma unroll
            for (int i = 0; i < 2; ++i)
                #pragma unroll
                for (int j = 0; j < 4; ++j)
                    acc[i][j] = __builtin_amdgcn_mfma_f32_16x16x32_bf16(
                        af[i], bcur[ks][j], acc[i][j], 0, 0, 0);
        }
    }

    // coalesced C epilogue: 4 passes of 64 cols reusing As.
    // C/D layout: col = lane&15, row = (lane>>4)*4 + reg  [m89-verified]
    #pragma unroll
    for (int qtr = 0; qtr < 4; ++qtr) {
        __syncthreads();
        if (wc == qtr) {
            #pragma unroll
            for (int i = 0; i < 2; ++i)
                #pragma unroll
                for (int j = 0; j < 4; ++j)
                    #pragma unroll
                    for (int v = 0; v < 4; ++v)
                        As[wr * 32 + i * 16 + lk * 4 + v][j * 16 + l15] =
                            (__bf16)acc[i][j][v];
        }
        __syncthreads();
        int row = tid >> 3, ch = tid & 7;
        if (bm + row < M)
            *(bf16x8*)(Cb + (size_t)(bm + row) * 256 + qtr * 64 + ch * 8) =
                *(const bf16x8*)&As[row][ch * 8];
    }
}

// ---- dispatch A: b%5==0 -> gemm tile (b/5), else csr_count chunk (512 e)
__global__ __launch_bounds__(512)
void gemm_count(const float* __restrict__ A, const __bf16* __restrict__ Bp,
                __bf16* __restrict__ Cb, int M,
                const int* __restrict__ ei, int* __restrict__ deg,
                int* __restrict__ slot, int E)
{
    __shared__ __bf16 As[64][72];            // 9.2 KB
    const int tid = threadIdx.x;
    const int b  = blockIdx.x;
    const int g5 = b / 5, m5 = b - g5 * 5;

    if (m5 != 0) {
        int e = (g5 * 4 + (m5 - 1)) * 512 + tid;
        if (e < E) slot[e] = atomicAdd(&deg[ei[E + e]], 1);
        return;
    }
    gemm_tile(A, Bp, Cb, M, g5 * 64, tid, As);
}

// ---- dispatch B: b%6==0 -> gemm tile (gstart + b/6), else fill chunk
// (1024 edges: thread handles e=base+tid and base+512+tid), atomic-free.
__global__ __launch_bounds__(512)
void gemm_fillk(const float* __restrict__ A, const __bf16* __restrict__ Bp,
                __bf16* __restrict__ Cb, int M, int gstart,
                const int* __restrict__ ei, const int* __restrict__ row_ptr,
                const int* __restrict__ slot, int* __restrict__ csr_src, int E)
{
    __shared__ __bf16 As[64][72];            // 9.2 KB
    const int tid = threadIdx.x;
    const int b  = blockIdx.x;
    const int g6 = b / 6, m6 = b - g6 * 6;

    if (m6 != 0) {
        int base = (g6 * 5 + (m6 - 1)) * 1024;
        #pragma unroll
        for (int it = 0; it < 2; ++it) {
            int e = base + it * 512 + tid;
            if (e < E)
                csr_src[row_ptr[ei[E + e]] + slot[e]] = ei[e];
        }
        return;
    }
    gemm_tile(A, Bp, Cb, M, (gstart + g6) * 64, tid, As);
}

// ---- layer 1 + layer-2 projection, fused. One wave per node.
// 8 lanes per edge x 32B/lane; inner loop pipelined x2 (r24-proven).
__global__ __launch_bounds__(256)
void sage1_fused(const int* __restrict__ row_ptr, const int* __restrict__ csr_src,
                 const __bf16* __restrict__ pq, const float* __restrict__ b1,
                 const float* __restrict__ W2l, const float* __restrict__ W2r,
                 float* __restrict__ r, float* __restrict__ s, int N)
{
    __shared__ float Wl[512], Wr[512];
    for (int i = threadIdx.x; i < 512; i += 256) {
        Wl[i] = W2l[i];
        Wr[i] = W2r[i];
    }
    __syncthreads();

    int wid  = threadIdx.x >> 6;
    int lane = threadIdx.x & 63;
    int g = lane >> 3;          // edge slot 0..7
    int l = lane & 7;           // feature block 0..7
    int n = blockIdx.x * 4 + wid;
    if (n >= N) return;
    int beg = row_ptr[n], end = row_ptr[n + 1];

    float a0[8] = {}, a1[8] = {};   // feats l*8+j and 64+l*8+j
    for (int eb = beg; eb < end; eb += 64) {
        int cnt = min(64, end - eb);
        int id = (eb + lane < end) ? csr_src[eb + lane] : 0;
        for (int t = 0; t < cnt; t += 16) {
            int src0 = __shfl(id, t + g);
            int src1 = __shfl(id, t + 8 + g);
            bool ok0 = (t + g < cnt);
            bool ok1 = (t + 8 + g < cnt);
            const __bf16* row0 = pq + (size_t)src0 * 256;
            const __bf16* row1 = pq + (size_t)src1 * 256;
            uint4 w0a, w1a, w0b, w1b;
            if (ok0) {
                w0a = *(const uint4*)(row0 + l * 8);
                w1a = *(const uint4*)(row0 + 64 + l * 8);
            }
            if (ok1) {
                w0b = *(const uint4*)(row1 + l * 8);
                w1b = *(const uint4*)(row1 + 64 + l * 8);
            }
            if (ok0) {
                a0[0] += bf16_lo(w0a.x); a0[1] += bf16_hi(w0a.x);
                a0[2] += bf16_lo(w0a.y); a0[3] += bf16_hi(w0a.y);
                a0[4] += bf16_lo(w0a.z); a0[5] += bf16_hi(w0a.z);
                a0[6] += bf16_lo(w0a.w); a0[7] += bf16_hi(w0a.w);
                a1[0] += bf16_lo(w1a.x); a1[1] += bf16_hi(w1a.x);
                a1[2] += bf16_lo(w1a.y); a1[3] += bf16_hi(w1a.y);
                a1[4] += bf16_lo(w1a.z); a1[5] += bf16_hi(w1a.z);
                a1[6] += bf16_lo(w1a.w); a1[7] += bf16_hi(w1a.w);
            }
            if (ok1) {
                a0[0] += bf16_lo(w0b.x); a0[1] += bf16_hi(w0b.x);
                a0[2] += bf16_lo(w0b.y); a0[3] += bf16_hi(w0b.y);
                a0[4] += bf16_lo(w0b.z); a0[5] += bf16_hi(w0b.z);
                a0[6] += bf16_lo(w0b.w); a0[7] += bf16_hi(w0b.w);
                a1[0] += bf16_lo(w1b.x); a1[1] += bf16_hi(w1b.x);
                a1[2] += bf16_lo(w1b.y); a1[3] += bf16_hi(w1b.y);
                a1[4] += bf16_lo(w1b.z); a1[5] += bf16_hi(w1b.z);
                a1[6] += bf16_lo(w1b.w); a1[7] += bf16_hi(w1b.w);
            }
        }
    }
    #pragma unroll
    for (int c = 0; c < 8; ++c) {
        a0[c] += __shfl_xor(a0[c], 8);  a1[c] += __shfl_xor(a1[c], 8);
        a0[c] += __shfl_xor(a0[c], 16); a1[c] += __shfl_xor(a1[c], 16);
        a0[c] += __shfl_xor(a0[c], 32); a1[c] += __shfl_xor(a1[c], 32);
    }

    float inv = 1.0f / fmaxf((float)(end - beg), 1.0f);
    const __bf16* qrow = pq + (size_t)n * 256 + 128;
    uint4  qw0 = *(const uint4*)(qrow + l * 8);
    uint4  qw1 = *(const uint4*)(qrow + 64 + l * 8);
    float4 bv00 = *(const float4*)(b1 + l * 8);
    float4 bv01 = *(const float4*)(b1 + l * 8 + 4);
    float4 bv10 = *(const float4*)(b1 + 64 + l * 8);
    float4 bv11 = *(const float4*)(b1 + 64 + l * 8 + 4);
    float h0[8], h1[8];
    h0[0] = fmaxf(a0[0] * inv + bv00.x + bf16_lo(qw0.x), 0.f);
    h0[1] = fmaxf(a0[1] * inv + bv00.y + bf16_hi(qw0.x), 0.f);
    h0[2] = fmaxf(a0[2] * inv + bv00.z + bf16_lo(qw0.y), 0.f);
    h0[3] = fmaxf(a0[3] * inv + bv00.w + bf16_hi(qw0.y), 0.f);
    h0[4] = fmaxf(a0[4] * inv + bv01.x + bf16_lo(qw0.z), 0.f);
    h0[5] = fmaxf(a0[5] * inv + bv01.y + bf16_hi(qw0.z), 0.f);
    h0[6] = fmaxf(a0[6] * inv + bv01.z + bf16_lo(qw0.w), 0.f);
    h0[7] = fmaxf(a0[7] * inv + bv01.w + bf16_hi(qw0.w), 0.f);
    h1[0] = fmaxf(a1[0] * inv + bv10.x + bf16_lo(qw1.x), 0.f);
    h1[1] = fmaxf(a1[1] * inv + bv10.y + bf16_hi(qw1.x), 0.f);
    h1[2] = fmaxf(a1[2] * inv + bv10.z + bf16_lo(qw1.y), 0.f);
    h1[3] = fmaxf(a1[3] * inv + bv10.w + bf16_hi(qw1.y), 0.f);
    h1[4] = fmaxf(a1[4] * inv + bv11.x + bf16_lo(qw1.z), 0.f);
    h1[5] = fmaxf(a1[5] * inv + bv11.y + bf16_hi(qw1.z), 0.f);
    h1[6] = fmaxf(a1[6] * inv + bv11.z + bf16_lo(qw1.w), 0.f);
    h1[7] = fmaxf(a1[7] * inv + bv11.w + bf16_hi(qw1.w), 0.f);

    float part[8];
    #pragma unroll
    for (int c = 0; c < 4; ++c) {
        float pl = 0.f, pr = 0.f;
        #pragma unroll
        for (int j = 0; j < 8; ++j) {
            pl = fmaf(h0[j], Wl[c * 128 + l * 8 + j], pl);
            pl = fmaf(h1[j], Wl[c * 128 + 64 + l * 8 + j], pl);
            pr = fmaf(h0[j], Wr[c * 128 + l * 8 + j], pr);
            pr = fmaf(h1[j], Wr[c * 128 + 64 + l * 8 + j], pr);
        }
        part[c] = pl; part[4 + c] = pr;
    }
    #pragma unroll
    for (int off = 4; off; off >>= 1)
        #pragma unroll
        for (int c = 0; c < 8; ++c)
            part[c] += __shfl_xor(part[c], off);
    if (lane == 0) {
        *(float4*)(r + (size_t)n * 4) = make_float4(part[0], part[1], part[2], part[3]);
        *(float4*)(s + (size_t)n * 4) = make_float4(part[4], part[5], part[6], part[7]);
    }
}

// ---- layer 2: out[n] = mean_{src} r[src] + b2 + s[n]
__global__ __launch_bounds__(256)
void sage2_gather(const int* __restrict__ row_ptr, const int* __restrict__ csr_src,
                  const float* __restrict__ r, const float* __restrict__ s,
                  const float* __restrict__ b2, float* __restrict__ out, int N)
{
    int t = blockIdx.x * 256 + threadIdx.x;
    if (t >= N * 4) return;
    int n = t >> 2, c = t & 3;
    int beg = row_ptr[n], end = row_ptr[n + 1];
    float acc = 0.f;
    for (int e = beg; e < end; ++e)
        acc += r[(size_t)csr_src[e] * 4 + c];
    out[t] = acc / fmaxf((float)(end - beg), 1.0f) + b2[c] + s[t];
}

extern "C" void kernel_launch(void* const* d_in, const int* in_sizes, int n_in,
                              void* d_out, int out_size, void* d_ws, size_t ws_size,
                              hipStream_t stream)
{
    const float* x   = (const float*)d_in[0];
    const int*   ei  = (const int*)d_in[1];
    const float* W1l = (const float*)d_in[2];
    const float* b1l = (const float*)d_in[3];
    const float* W1r = (const float*)d_in[4];
    const float* W2l = (const float*)d_in[5];
    const float* b2l = (const float*)d_in[6];
    const float* W2r = (const float*)d_in[7];
    float* out = (float*)d_out;

    const int N = in_sizes[0] / 768;   // 50000
    const int E = in_sizes[1] / 2;     // 800000
    const int NB = (N + 1023) / 1024;  // 49 scan blocks
    const int gblocks = (N + 63) / 64; // 782 gemm tiles (BN=256 full width)
    const int gA = 600;                // dispatch A tiles (count cover)
    const int gB = gblocks - gA;       // 182 dispatch B tiles (fill cover)
    // A: 4 chunks/tile x 512e = 1.23M cap >= 800K. B: 5 chunks/tile x 1024e
    // = 932K cap >= 800K. Both guarded by e<E.

    char* ws = (char*)d_ws;
    size_t off = 0;
    auto alloc = [&](size_t bytes) -> void* {
        void* pp = ws + off;
        off += (bytes + 255) & ~(size_t)255;
        return pp;
    };
    __bf16* pq      = (__bf16*)alloc((size_t)N * 256 * 2);
    float*  r       = (float*)alloc((size_t)N * 4 * 4);
    float*  s       = (float*)alloc((size_t)N * 4 * 4);
    __bf16* Bp      = (__bf16*)alloc((size_t)256 * 768 * 2);
    int*    deg     = (int*)alloc((size_t)N * 4);
    int*    row_ptr = (int*)alloc((size_t)(N + 1) * 4);
    int*    slot    = (int*)alloc((size_t)E * 4);
    int*    csr_src = (int*)alloc((size_t)E * 4);
    int*    partials= (int*)alloc((size_t)64 * 4);

    // ---- pack W fragment-major bf16 + zero deg
    prep<<<(256 * 768 + 255) / 256, 256, 0, stream>>>(W1l, W1r, Bp, deg, N);

    // ---- dispatch A: gemm tiles 0..599 + ALL csr_count chunks
    gemm_count<<<gA * 5, 512, 0, stream>>>(x, Bp, pq, N, ei, deg, slot, E);

    // ---- scans (only serial CSR cost left)
    scan1<<<NB, 1024, 0, stream>>>(deg, row_ptr, partials, N);
    scan23<<<NB, 1024, 0, stream>>>(row_ptr, partials, N, E, NB);

    // ---- dispatch B: gemm tiles 600..781 + ALL csr_fill chunks
    gemm_fillk<<<gB * 6, 512, 0, stream>>>(x, Bp, pq, N, gA,
                                           ei, row_ptr, slot, csr_src, E);

    // ---- layer 1 aggregate + epilogue + layer-2 projection (fused)
    sage1_fused<<<(N + 3) / 4, 256, 0, stream>>>(row_ptr, csr_src, pq, b1l,
                                                 W2l, W2r, r, s, N);

    // ---- layer 2 aggregate + epilogue
    sage2_gather<<<(N * 4 + 255) / 256, 256, 0, stream>>>(row_ptr, csr_src, r, s, b2l, out, N);
}

// Round 27
// 180.841 us; speedup vs baseline: 1.0236x; 1.0206x over previous
//
#include <hip/hip_runtime.h>

// ---------------------------------------------------------------------------
// TextGraphSAGE: 2-layer SAGEConv (mean aggr), N=50000, D=768, H=128, C=4,
// E=800000.
//  - project BEFORE aggregating (mean commutes with linear map)
//  - CSR gather instead of scatter atomics (r1: 102M float atomics = 77%)
//  - r17: atomic-free slot fill; r18: r8 gemm engine; r22/r23: count+fill
//    hidden under gemm halves (even 1:4 interleave); r24: sage1 2-deep
//    pipeline. r25/26 uneven split REGRESSED (dense atomics slow the
//    whole dispatch) -> reverted to r24 structure.
//  - r27: sage2_gather vectorized (one thread/node, float4 per edge:
//    4x fewer load instructions, same order -> bit-identical).
// ---------------------------------------------------------------------------

typedef __bf16 bf16x8 __attribute__((ext_vector_type(8)));
typedef float  f32x4  __attribute__((ext_vector_type(4)));

__device__ __forceinline__ float bf16_lo(uint32_t w) {
    union { uint32_t u; float f; } c; c.u = w << 16; return c.f;
}
__device__ __forceinline__ float bf16_hi(uint32_t w) {
    union { uint32_t u; float f; } c; c.u = w & 0xffff0000u; return c.f;
}

// ---- prep: pack W into fragment-major bf16 Bp[kg][col][8] (kg=k/8, 96x256x8)
//      element (col,k) -> Bp[(k>>3)*2048 + col*8 + (k&7)]; also zero deg.
__global__ __launch_bounds__(256)
void prep(const float* __restrict__ W1l, const float* __restrict__ W1r,
          __bf16* __restrict__ Bp, int* __restrict__ deg, int N)
{
    int i = blockIdx.x * 256 + threadIdx.x;
    if (i < N) deg[i] = 0;
    if (i < 256 * 768) {
        int col = i / 768, k = i - col * 768;
        float v = (col < 128) ? W1l[col * 768 + k] : W1r[(col - 128) * 768 + k];
        Bp[((k >> 3) << 11) + (col << 3) + (k & 7)] = (__bf16)v;
    }
}

// ---- scan step 1: per-1024-block exclusive scan + block totals
__global__ __launch_bounds__(1024)
void scan1(const int* __restrict__ deg, int* __restrict__ row_ptr,
           int* __restrict__ partials, int N)
{
    __shared__ int buf[1024];
    int i = blockIdx.x * 1024 + threadIdx.x;
    int v = (i < N) ? deg[i] : 0;
    int val = v;
    buf[threadIdx.x] = val;
    __syncthreads();
    for (int off = 1; off < 1024; off <<= 1) {
        int t = (threadIdx.x >= (unsigned)off) ? buf[threadIdx.x - off] : 0;
        __syncthreads();
        val += t;
        buf[threadIdx.x] = val;
        __syncthreads();
    }
    if (i < N) row_ptr[i] = val - v;
    if (threadIdx.x == 1023) partials[blockIdx.x] = val;
}

// ---- scan steps 2+3 merged
__global__ __launch_bounds__(1024)
void scan23(int* __restrict__ row_ptr, const int* __restrict__ partials,
            int N, int E, int nb)
{
    __shared__ int soff;
    int b = blockIdx.x;
    if (threadIdx.x < 64) {
        int lane = threadIdx.x;
        int v = (lane < nb) ? partials[lane] : 0;
        int s = v;
        #pragma unroll
        for (int off = 1; off < 64; off <<= 1) {
            int t = __shfl_up(s, off);
            if (lane >= off) s += t;
        }
        if (lane == b) soff = s - v;
    }
    __syncthreads();
    int off = soff;
    int i = b * 1024 + threadIdx.x;
    if (i < N) row_ptr[i] += off;
    if (b == 0 && threadIdx.x == 0) row_ptr[N] = E;
}

// ---- fused, block-interleaved: b%5==0 -> gemm tile (gstart + b/5);
// else -> edge chunk (count in MODE 0, fill in MODE 1), atomic-free fill.
template<int MODE>
__global__ __launch_bounds__(512)
void gemm_mixed(const float* __restrict__ A, const __bf16* __restrict__ Bp,
                __bf16* __restrict__ Cb, int M, int gstart,
                const int* __restrict__ ei, int* __restrict__ deg,
                const int* __restrict__ row_ptr, int* __restrict__ slot,
                int* __restrict__ csr_src, int E)
{
    constexpr int LDK = 72;                  // +8 bf16 pad (144B row stride)
    __shared__ __bf16 As[64][LDK];           // 9.2 KB (staging + C-stage)
    const int tid = threadIdx.x;
    const int b  = blockIdx.x;
    const int g5 = b / 5, m5 = b - g5 * 5;

    if (m5 != 0) {
        // --------- edge chunk: one edge per thread ---------
        int e = (g5 * 4 + (m5 - 1)) * 512 + tid;
        if (e < E) {
            if (MODE == 0) {                 // count + slot
                slot[e] = atomicAdd(&deg[ei[E + e]], 1);
            } else {                         // fill, atomic-free
                csr_src[row_ptr[ei[E + e]] + slot[e]] = ei[e];
            }
        }
        return;
    }

    // ---------------- gemm path (r8 engine, 1-deep prefetch) ----------------
    const int bm   = (gstart + g5) * 64;
    const int lane = tid & 63;
    const int wave = tid >> 6;               // 0..7
    const int wr = wave >> 2, wc = wave & 3; // wave tile: 32 rows x 64 cols
    const int l15 = lane & 15;
    const int lk  = lane >> 4;               // 0..3

    f32x4 acc[2][4] = {};
    float4 apref[2];

    const int arow = tid >> 3;               // 0..63
    const int akc  = (tid & 7) << 3;         // 0..56
    const __bf16* bbase = Bp + ((size_t)(wc * 64 + l15) << 3) + ((size_t)lk << 11);

    auto load_A = [&](int k0) {
        if (bm + arow < M) {
            const float* src = A + (size_t)(bm + arow) * 768 + k0 + akc;
            apref[0] = *(const float4*)src;
            apref[1] = *(const float4*)(src + 4);
        } else {
            apref[0] = make_float4(0.f, 0.f, 0.f, 0.f);
            apref[1] = make_float4(0.f, 0.f, 0.f, 0.f);
        }
    };

    load_A(0);
    for (int kt = 0; kt < 12; ++kt) {
        if (kt) __syncthreads();             // MFMA of kt-1 done with LDS
        {
            float4 f0 = apref[0], f1 = apref[1];
            bf16x8 bb;
            bb[0] = (__bf16)f0.x; bb[1] = (__bf16)f0.y;
            bb[2] = (__bf16)f0.z; bb[3] = (__bf16)f0.w;
            bb[4] = (__bf16)f1.x; bb[5] = (__bf16)f1.y;
            bb[6] = (__bf16)f1.z; bb[7] = (__bf16)f1.w;
            *(bf16x8*)&As[arow][akc] = bb;
        }
        __syncthreads();
        if (kt < 11) load_A((kt + 1) * 64);  // A burst in flight across MFMA

        bf16x8 bcur[2][4];
        #pragma unroll
        for (int ks = 0; ks < 2; ++ks)
            #pragma unroll
            for (int j = 0; j < 4; ++j)
                bcur[ks][j] = *(const bf16x8*)(bbase +
                    (((size_t)(kt * 8 + ks * 4) << 11) + ((size_t)j << 7)));

        #pragma unroll
        for (int ks = 0; ks < 2; ++ks) {
            int koff = ks * 32 + lk * 8;
            bf16x8 af[2];
            #pragma unroll
            for (int i = 0; i < 2; ++i)
                af[i] = *(const bf16x8*)&As[wr * 32 + i * 16 + l15][koff];
            #pragma unroll
            for (int i = 0; i < 2; ++i)
                #pragma unroll
                for (int j = 0; j < 4; ++j)
                    acc[i][j] = __builtin_amdgcn_mfma_f32_16x16x32_bf16(
                        af[i], bcur[ks][j], acc[i][j], 0, 0, 0);
        }
    }

    // ---- coalesced C epilogue: 4 passes of 64 cols reusing As.
    // C/D layout: col = lane&15, row = (lane>>4)*4 + reg  [m89-verified]
    #pragma unroll
    for (int qtr = 0; qtr < 4; ++qtr) {
        __syncthreads();                     // prev pass stores / MFMA done
        if (wc == qtr) {
            #pragma unroll
            for (int i = 0; i < 2; ++i)
                #pragma unroll
                for (int j = 0; j < 4; ++j)
                    #pragma unroll
                    for (int v = 0; v < 4; ++v)
                        As[wr * 32 + i * 16 + lk * 4 + v][j * 16 + l15] =
                            (__bf16)acc[i][j][v];
        }
        __syncthreads();
        int row = tid >> 3, ch = tid & 7;
        if (bm + row < M)
            *(bf16x8*)(Cb + (size_t)(bm + row) * 256 + qtr * 64 + ch * 8) =
                *(const bf16x8*)&As[row][ch * 8];
    }
}

// ---- layer 1 + layer-2 projection, fused. One wave per node.
// 8 lanes per edge x 32B/lane; inner loop pipelined x2 (r24-proven).
__global__ __launch_bounds__(256)
void sage1_fused(const int* __restrict__ row_ptr, const int* __restrict__ csr_src,
                 const __bf16* __restrict__ pq, const float* __restrict__ b1,
                 const float* __restrict__ W2l, const float* __restrict__ W2r,
                 float* __restrict__ r, float* __restrict__ s, int N)
{
    __shared__ float Wl[512], Wr[512];
    for (int i = threadIdx.x; i < 512; i += 256) {
        Wl[i] = W2l[i];
        Wr[i] = W2r[i];
    }
    __syncthreads();

    int wid  = threadIdx.x >> 6;
    int lane = threadIdx.x & 63;
    int g = lane >> 3;          // edge slot 0..7
    int l = lane & 7;           // feature block 0..7
    int n = blockIdx.x * 4 + wid;
    if (n >= N) return;
    int beg = row_ptr[n], end = row_ptr[n + 1];

    float a0[8] = {}, a1[8] = {};   // feats l*8+j and 64+l*8+j
    for (int eb = beg; eb < end; eb += 64) {
        int cnt = min(64, end - eb);
        int id = (eb + lane < end) ? csr_src[eb + lane] : 0;
        for (int t = 0; t < cnt; t += 16) {
            int src0 = __shfl(id, t + g);
            int src1 = __shfl(id, t + 8 + g);
            bool ok0 = (t + g < cnt);
            bool ok1 = (t + 8 + g < cnt);
            const __bf16* row0 = pq + (size_t)src0 * 256;
            const __bf16* row1 = pq + (size_t)src1 * 256;
            uint4 w0a, w1a, w0b, w1b;
            if (ok0) {
                w0a = *(const uint4*)(row0 + l * 8);
                w1a = *(const uint4*)(row0 + 64 + l * 8);
            }
            if (ok1) {
                w0b = *(const uint4*)(row1 + l * 8);
                w1b = *(const uint4*)(row1 + 64 + l * 8);
            }
            if (ok0) {
                a0[0] += bf16_lo(w0a.x); a0[1] += bf16_hi(w0a.x);
                a0[2] += bf16_lo(w0a.y); a0[3] += bf16_hi(w0a.y);
                a0[4] += bf16_lo(w0a.z); a0[5] += bf16_hi(w0a.z);
                a0[6] += bf16_lo(w0a.w); a0[7] += bf16_hi(w0a.w);
                a1[0] += bf16_lo(w1a.x); a1[1] += bf16_hi(w1a.x);
                a1[2] += bf16_lo(w1a.y); a1[3] += bf16_hi(w1a.y);
                a1[4] += bf16_lo(w1a.z); a1[5] += bf16_hi(w1a.z);
                a1[6] += bf16_lo(w1a.w); a1[7] += bf16_hi(w1a.w);
            }
            if (ok1) {
                a0[0] += bf16_lo(w0b.x); a0[1] += bf16_hi(w0b.x);
                a0[2] += bf16_lo(w0b.y); a0[3] += bf16_hi(w0b.y);
                a0[4] += bf16_lo(w0b.z); a0[5] += bf16_hi(w0b.z);
                a0[6] += bf16_lo(w0b.w); a0[7] += bf16_hi(w0b.w);
                a1[0] += bf16_lo(w1b.x); a1[1] += bf16_hi(w1b.x);
                a1[2] += bf16_lo(w1b.y); a1[3] += bf16_hi(w1b.y);
                a1[4] += bf16_lo(w1b.z); a1[5] += bf16_hi(w1b.z);
                a1[6] += bf16_lo(w1b.w); a1[7] += bf16_hi(w1b.w);
            }
        }
    }
    #pragma unroll
    for (int c = 0; c < 8; ++c) {
        a0[c] += __shfl_xor(a0[c], 8);  a1[c] += __shfl_xor(a1[c], 8);
        a0[c] += __shfl_xor(a0[c], 16); a1[c] += __shfl_xor(a1[c], 16);
        a0[c] += __shfl_xor(a0[c], 32); a1[c] += __shfl_xor(a1[c], 32);
    }

    float inv = 1.0f / fmaxf((float)(end - beg), 1.0f);
    const __bf16* qrow = pq + (size_t)n * 256 + 128;
    uint4  qw0 = *(const uint4*)(qrow + l * 8);
    uint4  qw1 = *(const uint4*)(qrow + 64 + l * 8);
    float4 bv00 = *(const float4*)(b1 + l * 8);
    float4 bv01 = *(const float4*)(b1 + l * 8 + 4);
    float4 bv10 = *(const float4*)(b1 + 64 + l * 8);
    float4 bv11 = *(const float4*)(b1 + 64 + l * 8 + 4);
    float h0[8], h1[8];
    h0[0] = fmaxf(a0[0] * inv + bv00.x + bf16_lo(qw0.x), 0.f);
    h0[1] = fmaxf(a0[1] * inv + bv00.y + bf16_hi(qw0.x), 0.f);
    h0[2] = fmaxf(a0[2] * inv + bv00.z + bf16_lo(qw0.y), 0.f);
    h0[3] = fmaxf(a0[3] * inv + bv00.w + bf16_hi(qw0.y), 0.f);
    h0[4] = fmaxf(a0[4] * inv + bv01.x + bf16_lo(qw0.z), 0.f);
    h0[5] = fmaxf(a0[5] * inv + bv01.y + bf16_hi(qw0.z), 0.f);
    h0[6] = fmaxf(a0[6] * inv + bv01.z + bf16_lo(qw0.w), 0.f);
    h0[7] = fmaxf(a0[7] * inv + bv01.w + bf16_hi(qw0.w), 0.f);
    h1[0] = fmaxf(a1[0] * inv + bv10.x + bf16_lo(qw1.x), 0.f);
    h1[1] = fmaxf(a1[1] * inv + bv10.y + bf16_hi(qw1.x), 0.f);
    h1[2] = fmaxf(a1[2] * inv + bv10.z + bf16_lo(qw1.y), 0.f);
    h1[3] = fmaxf(a1[3] * inv + bv10.w + bf16_hi(qw1.y), 0.f);
    h1[4] = fmaxf(a1[4] * inv + bv11.x + bf16_lo(qw1.z), 0.f);
    h1[5] = fmaxf(a1[5] * inv + bv11.y + bf16_hi(qw1.z), 0.f);
    h1[6] = fmaxf(a1[6] * inv + bv11.z + bf16_lo(qw1.w), 0.f);
    h1[7] = fmaxf(a1[7] * inv + bv11.w + bf16_hi(qw1.w), 0.f);

    float part[8];
    #pragma unroll
    for (int c = 0; c < 4; ++c) {
        float pl = 0.f, pr = 0.f;
        #pragma unroll
        for (int j = 0; j < 8; ++j) {
            pl = fmaf(h0[j], Wl[c * 128 + l * 8 + j], pl);
            pl = fmaf(h1[j], Wl[c * 128 + 64 + l * 8 + j], pl);
            pr = fmaf(h0[j], Wr[c * 128 + l * 8 + j], pr);
            pr = fmaf(h1[j], Wr[c * 128 + 64 + l * 8 + j], pr);
        }
        part[c] = pl; part[4 + c] = pr;
    }
    #pragma unroll
    for (int off = 4; off; off >>= 1)
        #pragma unroll
        for (int c = 0; c < 8; ++c)
            part[c] += __shfl_xor(part[c], off);
    if (lane == 0) {
        *(float4*)(r + (size_t)n * 4) = make_float4(part[0], part[1], part[2], part[3]);
        *(float4*)(s + (size_t)n * 4) = make_float4(part[4], part[5], part[6], part[7]);
    }
}

// ---- layer 2: out[n] = mean_{src} r[src] + b2 + s[n]
// one thread per node, float4 per edge (4x fewer loads than per-channel).
__global__ __launch_bounds__(256)
void sage2_gather(const int* __restrict__ row_ptr, const int* __restrict__ csr_src,
                  const float* __restrict__ r, const float* __restrict__ s,
                  const float* __restrict__ b2, float* __restrict__ out, int N)
{
    int n = blockIdx.x * 256 + threadIdx.x;
    if (n >= N) return;
    int beg = row_ptr[n], end = row_ptr[n + 1];
    float4 acc = make_float4(0.f, 0.f, 0.f, 0.f);
    for (int e = beg; e < end; ++e) {
        float4 v = *(const float4*)(r + (size_t)csr_src[e] * 4);
        acc.x += v.x; acc.y += v.y; acc.z += v.z; acc.w += v.w;
    }
    float inv = 1.0f / fmaxf((float)(end - beg), 1.0f);
    float4 sv = *(const float4*)(s + (size_t)n * 4);
    float4 o;
    o.x = acc.x * inv + b2[0] + sv.x;
    o.y = acc.y * inv + b2[1] + sv.y;
    o.z = acc.z * inv + b2[2] + sv.z;
    o.w = acc.w * inv + b2[3] + sv.w;
    *(float4*)(out + (size_t)n * 4) = o;
}

extern "C" void kernel_launch(void* const* d_in, const int* in_sizes, int n_in,
                              void* d_out, int out_size, void* d_ws, size_t ws_size,
                              hipStream_t stream)
{
    const float* x   = (const float*)d_in[0];
    const int*   ei  = (const int*)d_in[1];
    const float* W1l = (const float*)d_in[2];
    const float* b1l = (const float*)d_in[3];
    const float* W1r = (const float*)d_in[4];
    const float* W2l = (const float*)d_in[5];
    const float* b2l = (const float*)d_in[6];
    const float* W2r = (const float*)d_in[7];
    float* out = (float*)d_out;

    const int N = in_sizes[0] / 768;   // 50000
    const int E = in_sizes[1] / 2;     // 800000
    const int NB = (N + 1023) / 1024;  // 49 scan blocks
    const int gblocks = (N + 63) / 64; // 782 gemm tiles (BN=256 full width)
    const int ghalf1  = gblocks / 2;   // 391 tiles in dispatch A
    const int ghalf2  = gblocks - ghalf1; // 391 tiles in dispatch B
    // each dispatch: 4 chunks/tile x 512e = 1564 chunks >= 1563 needed.

    char* ws = (char*)d_ws;
    size_t off = 0;
    auto alloc = [&](size_t bytes) -> void* {
        void* pp = ws + off;
        off += (bytes + 255) & ~(size_t)255;
        return pp;
    };
    __bf16* pq      = (__bf16*)alloc((size_t)N * 256 * 2);
    float*  r       = (float*)alloc((size_t)N * 4 * 4);
    float*  s       = (float*)alloc((size_t)N * 4 * 4);
    __bf16* Bp      = (__bf16*)alloc((size_t)256 * 768 * 2);
    int*    deg     = (int*)alloc((size_t)N * 4);
    int*    row_ptr = (int*)alloc((size_t)(N + 1) * 4);
    int*    slot    = (int*)alloc((size_t)E * 4);
    int*    csr_src = (int*)alloc((size_t)E * 4);
    int*    partials= (int*)alloc((size_t)64 * 4);

    // ---- pack W fragment-major bf16 + zero deg
    prep<<<(256 * 768 + 255) / 256, 256, 0, stream>>>(W1l, W1r, Bp, deg, N);

    // ---- dispatch A: gemm tiles 0..ghalf1-1 + ALL csr_count chunks
    gemm_mixed<0><<<ghalf1 * 5, 512, 0, stream>>>(x, Bp, pq, N, 0,
                                                  ei, deg, row_ptr, slot,
                                                  csr_src, E);

    // ---- scans (only serial CSR cost left)
    scan1<<<NB, 1024, 0, stream>>>(deg, row_ptr, partials, N);
    scan23<<<NB, 1024, 0, stream>>>(row_ptr, partials, N, E, NB);

    // ---- dispatch B: gemm tiles ghalf1..gblocks-1 + ALL csr_fill chunks
    gemm_mixed<1><<<ghalf2 * 5, 512, 0, stream>>>(x, Bp, pq, N, ghalf1,
                                                  ei, deg, row_ptr, slot,
                                                  csr_src, E);

    // ---- layer 1 aggregate + epilogue + layer-2 projection (fused)
    sage1_fused<<<(N + 3) / 4, 256, 0, stream>>>(row_ptr, csr_src, pq, b1l,
                                                 W2l, W2r, r, s, N);

    // ---- layer 2 aggregate + epilogue
    sage2_gather<<<(N + 255) / 256, 256, 0, stream>>>(row_ptr, csr_src, r, s, b2l, out, N);
}